// Round 4
// baseline (142.123 us; speedup 1.0000x reference)
//
#include <hip/hip_runtime.h>
#include <hip/hip_bf16.h>

#define B 128
#define N 32
#define DO 128
#define NA 16
#define H 4
#define DK 64
#define DV 64
#define LN_EPS 1e-5f
#define NEG_SLOPE 0.01f

typedef unsigned short u16;
typedef __attribute__((ext_vector_type(8))) short bf16x8;
typedef __attribute__((ext_vector_type(4))) float f32x4;

__device__ __forceinline__ float leaky(float x) {
    return x >= 0.f ? x : NEG_SLOPE * x;
}

__device__ __forceinline__ u16 f2bf(float x) {
    union { float f; unsigned int u; } v; v.f = x;
    unsigned int r = (v.u + 0x7FFF + ((v.u >> 16) & 1)) >> 16;
    return (u16)r;
}

__device__ __forceinline__ float bf2f(u16 x) {
    union { unsigned int u; float f; } v; v.u = ((unsigned int)x) << 16;
    return v.f;
}

// DPP-based partial add on the VALU pipe.
template<int CTRL>
__device__ __forceinline__ float dppadd(float x) {
    return x + __int_as_float(__builtin_amdgcn_update_dpp(
        0, __float_as_int(x), CTRL, 0xF, 0xF, true));
}

// readlane broadcast (lane index compile-time in unrolled loops)
__device__ __forceinline__ float rdlane(float x, int lane) {
    return __int_as_float(__builtin_amdgcn_readlane(__float_as_int(x), lane));
}

// ---------------------------------------------------------------------------
// kP: one-shot weight prep, 7 blocks x 256 threads. (unchanged)
// ---------------------------------------------------------------------------
__global__ __launch_bounds__(256) void kP(
    const float* __restrict__ Wk, const float* __restrict__ Wq,
    const float* __restrict__ Wv, const float* __restrict__ W_se,
    const float* __restrict__ W_sape, const float* __restrict__ ln_g,
    const float* __restrict__ ln_b, const float* __restrict__ W_f1,
    u16* __restrict__ wTb, u16* __restrict__ wseT, u16* __restrict__ wsapeT,
    u16* __restrict__ sapeTail, u16* __restrict__ wTg,
    float* __restrict__ GW, float* __restrict__ BW)
{
    const int blk = blockIdx.x;
    const int t   = threadIdx.x;
    __shared__ float wls[8192];

    if (blk < 4) {
        const int hh = blk;
        for (int m = 0; m < 3; m++) {
            const float* src = (m == 0 ? Wq : (m == 1 ? Wk : Wv)) + hh * 8192;
            for (int idx = t; idx < 2048; idx += 256)
                ((float4*)wls)[idx] = ((const float4*)src)[idx];
            __syncthreads();
            u16* dst = wTb + (hh * 3 + m) * 8192;
            for (int idx = t; idx < 8192; idx += 256) {
                const int n = idx >> 7, k = idx & 127;
                dst[idx] = f2bf(wls[k * 64 + n]);
            }
            __syncthreads();
        }
    } else if (blk == 4 || blk == 5) {
        const float* src = (blk == 4) ? W_se : W_sape;
        u16* dst = (blk == 4) ? wseT : wsapeT;
        for (int chunk = 0; chunk < 2; chunk++) {
            const int k0 = chunk * 64;
            for (int idx = t; idx < 2048; idx += 256)
                ((float4*)wls)[idx] = ((const float4*)(src + k0 * 128))[idx];
            __syncthreads();
            for (int idx = t; idx < 8192; idx += 256) {
                const int n = idx >> 6, kk = idx & 63;
                dst[n * 128 + k0 + kk] = f2bf(wls[kk * 128 + n]);
            }
            __syncthreads();
        }
        if (blk == 5) {
            for (int idx = t; idx < 2048; idx += 256)
                wls[idx] = W_sape[128 * 128 + idx];
            __syncthreads();
            for (int idx = t; idx < 4096; idx += 256) {
                const int n = idx >> 5, kk = idx & 31;
                sapeTail[n * 32 + kk] = (kk < 16) ? f2bf(wls[kk * 128 + n]) : (u16)0;
            }
        }
    } else {
        for (int idx = t; idx < 16384; idx += 256) {
            const int hh = idx >> 12, c = (idx >> 6) & 63, ee = idx & 63;
            wTg[idx] = f2bf(ln_g[hh * 64 + ee] * W_f1[(hh * 64 + ee) * 64 + c]);
        }
        {   // GW fp32-exact
            const int hh = t >> 6, c = t & 63;
            float g = 0.f;
            #pragma unroll 4
            for (int ee = 0; ee < 64; ee++)
                g += ln_g[hh * 64 + ee] * W_f1[(hh * 64 + ee) * 64 + c];
            GW[t] = g;
        }
        {   // BW fp32-exact via partials
            const int c = t & 63, qq = t >> 6;
            float bacc = 0.f;
            #pragma unroll 4
            for (int r = 0; r < 64; r++)
                bacc += ln_b[qq * 64 + r] * W_f1[(qq * 64 + r) * 64 + c];
            wls[qq * 64 + c] = bacc;
        }
        __syncthreads();
        if (t < 64) BW[t] = wls[t] + wls[64 + t] + wls[128 + t] + wls[192 + t];
    }
}

// ---------------------------------------------------------------------------
// Mega kernel B: 128 blocks (one per b) x 1024 threads, ALL 4 heads in-block.
//  - phase -1 computed once per b (was duplicated 4x)
//  - every phase occupies all 16 waves (head hh = wave>>2, role r = wave&3)
//  - SG/DG stay in LDS (overlaying dead buffers); kC fused as tail via
//    __syncthreads (no cross-block sync)
// LDS map (bytes), total 146432:
//  [0..39936)  : stage/-1/A inputs (sST 8704|actA 2560|polA 2560|sSE 8704|
//                sXA 8704|sXP 8704);  DG[h][j][e] f32 32768 overlays from
//                phase C (region dead after phase A)
//  per-h region at 39936 + h*26624:
//    qb 4608 | kb 4608   (S32 f32 8704 overlays qb..kb from phase C)
//    diffb 4608 @9216 | Sb 4608 @13824 | avaT 5120 @18432 | wb 2560 @23552
//    SG[i][e] f32 8192 overlays avaT..end from phase D
// ---------------------------------------------------------------------------
__global__ __launch_bounds__(1024, 4) void kB(
    const float* __restrict__ states, const float* __restrict__ actions,
    const float* __restrict__ policies,
    const float* __restrict__ b_se, const float* __restrict__ b_sape,
    const u16* __restrict__ wTb, const u16* __restrict__ wseT,
    const u16* __restrict__ wsapeT, const u16* __restrict__ sapeTail,
    const u16* __restrict__ wTg,
    float* __restrict__ w_out,
    float* __restrict__ sumS, float* __restrict__ sumS2,
    float* __restrict__ sumD, float* __restrict__ sumD2,
    float* __restrict__ dotSD,
    const float* __restrict__ GW, const float* __restrict__ BW,
    const float* __restrict__ W_f2, float* __restrict__ value)
{
    const int b    = blockIdx.x;
    const int t    = threadIdx.x;
    const int wave = t >> 6;
    const int e    = t & 63;
    const int q16  = e >> 4;
    const int l16  = e & 15;
    const int hh   = wave >> 2;   // head for phases A..D
    const int r    = wave & 3;    // role within head

    __shared__ alignas(16) char sm[146432];
    u16*   const sST  = (u16*)(sm + 0);
    u16*   const actA = (u16*)(sm + 8704);
    u16*   const polA = (u16*)(sm + 11264);
    u16*   const sSE  = (u16*)(sm + 13824);
    u16*   const sXA  = (u16*)(sm + 22528);
    u16*   const sXP  = (u16*)(sm + 31232);
    float* const DGf  = (float*)(sm + 0);                 // [h][j][e] h*2048+j*64+e
    char*  const ph   = sm + 39936 + hh * 26624;          // this wave's head region
    u16*   const qb_h    = (u16*)(ph + 0);
    u16*   const kb_h    = (u16*)(ph + 4608);
    float* const S32_h   = (float*)(ph + 0);              // overlays qb/kb (phase C+)
    u16*   const diffb_h = (u16*)(ph + 9216);
    u16*   const Sb_h    = (u16*)(ph + 13824);
    u16*   const avaT_h  = (u16*)(ph + 18432);
    u16*   const wb_h    = (u16*)(ph + 23552);
    // whole-block accessors (tail iterates all heads)
    #define SGF(h)  ((float*)(sm + 39936 + (h) * 26624 + 18432))  // [i][e] i*64+e
    #define PHH(h)  (sm + 39936 + (h) * 26624)

    // ---- prefetch phase -1 B-operands (wave-tile: mt=wave>>3, nt=wave&7)
    const int mtP   = wave >> 3, ntP = wave & 7;
    const int bcolP = ntP * 16 + l16;
    bf16x8 pse[4];
    {
        const u16* bse_p = wseT + bcolP * 128;
        #pragma unroll
        for (int ks = 0; ks < 4; ks++)
            pse[ks] = *(const bf16x8*)&bse_p[ks * 32 + q16 * 8];
    }
    const bf16x8 btP   = *(const bf16x8*)&sapeTail[bcolP * 32 + q16 * 8];
    const float  bse_c = b_se[bcolP];
    const float  bsp_c = b_sape[bcolP];

    // ---- stage: states/actions/policies -> bf16 LDS
    {
        const int rr = t >> 5, c4 = (t & 31) * 4;
        const float4 s4 = *(const float4*)&states[(b * 32 + rr) * 128 + c4];
        ushort4 u;
        u.x = f2bf(s4.x); u.y = f2bf(s4.y); u.z = f2bf(s4.z); u.w = f2bf(s4.w);
        *(ushort4*)&sST[rr * 136 + c4] = u;
    }
    if (t < 512) {
        const int rr = t >> 4, c = t & 15;
        actA[rr * 40 + c]      = f2bf(actions[(b * 32 + rr) * 16 + c]);
        actA[rr * 40 + 16 + c] = 0;
    } else {
        const int t2 = t - 512, rr = t2 >> 4, c = t2 & 15;
        polA[rr * 40 + c]      = f2bf(policies[(b * 32 + rr) * 16 + c]);
        polA[rr * 40 + 16 + c] = 0;
    }
    bf16x8 psp[4];
    {
        const u16* bsp_p = wsapeT + bcolP * 128;
        #pragma unroll
        for (int ks = 0; ks < 4; ks++)
            psp[ks] = *(const bf16x8*)&bsp_p[ks * 32 + q16 * 8];
    }
    __syncthreads();

    // ---- phase -1: se/xa/xp — ONCE per b (h-independent)
    {
        const int arow = mtP * 16 + l16;
        const int bcol = bcolP;
        f32x4 a_se = {0.f,0.f,0.f,0.f}, a_sp = {0.f,0.f,0.f,0.f};
        f32x4 a_oa = {0.f,0.f,0.f,0.f}, a_op = {0.f,0.f,0.f,0.f};
        #pragma unroll
        for (int ks = 0; ks < 4; ks++) {
            const bf16x8 af = *(const bf16x8*)&sST[arow * 136 + ks * 32 + q16 * 8];
            a_se = __builtin_amdgcn_mfma_f32_16x16x32_bf16(af, pse[ks], a_se, 0, 0, 0);
            a_sp = __builtin_amdgcn_mfma_f32_16x16x32_bf16(af, psp[ks], a_sp, 0, 0, 0);
        }
        a_oa = __builtin_amdgcn_mfma_f32_16x16x32_bf16(
            *(const bf16x8*)&actA[arow * 40 + q16 * 8], btP, a_oa, 0, 0, 0);
        a_op = __builtin_amdgcn_mfma_f32_16x16x32_bf16(
            *(const bf16x8*)&polA[arow * 40 + q16 * 8], btP, a_op, 0, 0, 0);
        const int r0 = mtP * 16 + q16 * 4;
        #pragma unroll
        for (int v = 0; v < 4; v++) {
            sSE[(r0 + v) * 136 + bcol] = f2bf(leaky(a_se[v] + bse_c));
            sXA[(r0 + v) * 136 + bcol] = f2bf(leaky(a_sp[v] + a_oa[v] + bsp_c));
            sXP[(r0 + v) * 136 + bcol] = f2bf(leaky(a_sp[v] + a_op[v] + bsp_c));
        }
    }
    __syncthreads();

    // ---- phase A: q,k,ava,avp — role r owns one matrix, 8 tiles (K=128)
    //      r=0: q (X=sSE,W=Wq)  r=1: k (sSE,Wk)  r=2: ava (sXA,Wv)  r=3: avp (sXP,Wv)
    f32x4 acc[8];
    {
        const u16* X = (r <= 1) ? sSE : (r == 2 ? sXA : sXP);
        const int widx = (r == 0) ? 0 : (r == 1 ? 1 : 2);
        #pragma unroll
        for (int p = 0; p < 8; p++) {
            const int mt = p >> 2, nt = p & 3;
            const int arow = mt * 16 + l16;
            const u16* wsrc = wTb + ((hh * 3 + widx) * 64 + nt * 16 + l16) * 128;
            f32x4 a = {0.f, 0.f, 0.f, 0.f};
            #pragma unroll
            for (int ks = 0; ks < 4; ks++) {
                const bf16x8 af = *(const bf16x8*)&X[arow * 136 + ks * 32 + q16 * 8];
                const bf16x8 bf = *(const bf16x8*)&wsrc[ks * 32 + q16 * 8];
                a = __builtin_amdgcn_mfma_f32_16x16x32_bf16(af, bf, a, 0, 0, 0);
            }
            acc[p] = a;
        }
        #pragma unroll
        for (int p = 0; p < 8; p++) {
            const int mt = p >> 2, nt = p & 3;
            const int c  = nt * 16 + l16;
            const int r0 = mt * 16 + q16 * 4;
            if (r == 0) {
                #pragma unroll
                for (int v = 0; v < 4; v++) qb_h[(r0 + v) * 72 + c] = f2bf(acc[p][v]);
            } else if (r == 1) {
                #pragma unroll
                for (int v = 0; v < 4; v++) kb_h[(r0 + v) * 72 + c] = f2bf(acc[p][v]);
            } else if (r == 2) {
                #pragma unroll
                for (int v = 0; v < 4; v++) avaT_h[c * 40 + (r0 + v)] = f2bf(acc[p][v]);
            } // r==3 (avp) held in regs for diff
        }
    }
    __syncthreads();

    // ---- phase B: softmax (r=0,1) | diff (r=3) | wTg prefetch (r>=2)
    bf16x8 pwg[4][2];
    if (r >= 2) {
        #pragma unroll
        for (int nt = 0; nt < 4; nt++) {
            const u16* wgp = wTg + (hh * 64 + nt * 16 + l16) * 64;
            #pragma unroll
            for (int ks = 0; ks < 2; ks++)
                pwg[nt][ks] = *(const bf16x8*)&wgp[ks * 32 + q16 * 8];
        }
    }
    if (r <= 1) {
        const int mt = r;
        f32x4 s0 = {0.f,0.f,0.f,0.f}, s1 = {0.f,0.f,0.f,0.f};
        #pragma unroll
        for (int ks = 0; ks < 2; ks++) {
            const bf16x8 af = *(const bf16x8*)&qb_h[(mt * 16 + l16) * 72 + ks * 32 + q16 * 8];
            const bf16x8 b0 = *(const bf16x8*)&kb_h[l16 * 72 + ks * 32 + q16 * 8];
            const bf16x8 b1 = *(const bf16x8*)&kb_h[(16 + l16) * 72 + ks * 32 + q16 * 8];
            s0 = __builtin_amdgcn_mfma_f32_16x16x32_bf16(af, b0, s0, 0, 0, 0);
            s1 = __builtin_amdgcn_mfma_f32_16x16x32_bf16(af, b1, s1, 0, 0, 0);
        }
        #pragma unroll
        for (int v = 0; v < 4; v++) {
            float a0 = s0[v] * 0.125f, a1 = s1[v] * 0.125f;
            float mx = fmaxf(a0, a1);
            #pragma unroll
            for (int m = 1; m < 16; m <<= 1) mx = fmaxf(mx, __shfl_xor(mx, m));
            float e0 = __expf(a0 - mx), e1 = __expf(a1 - mx);
            float sm2 = e0 + e1;
            #pragma unroll
            for (int m = 1; m < 16; m <<= 1) sm2 += __shfl_xor(sm2, m);
            const float inv = 1.f / sm2;
            e0 *= inv; e1 *= inv;
            const int i = mt * 16 + q16 * 4 + v;
            wb_h[i * 40 + l16]      = f2bf(e0);
            wb_h[i * 40 + 16 + l16] = f2bf(e1);
            w_out[(((b * 4 + hh) * 32) + i) * 32 + l16]      = e0;
            w_out[(((b * 4 + hh) * 32) + i) * 32 + 16 + l16] = e1;
        }
    } else if (r == 3) {
        #pragma unroll
        for (int p = 0; p < 8; p++) {
            const int mt = p >> 2, nt = p & 3;
            const int c  = nt * 16 + l16;
            const int r0 = mt * 16 + q16 * 4;
            #pragma unroll
            for (int v = 0; v < 4; v++) {
                const float av = bf2f(avaT_h[c * 40 + (r0 + v)]);
                diffb_h[(r0 + v) * 72 + c] = f2bf(acc[p][v] - av);
            }
        }
    }
    __syncthreads();

    // ---- phase C: S = w@ava (r=0,1: mt=r, nt=0..3) | DG = diff@Wg (r=2,3)
    if (r <= 1) {
        const int mt = r;
        const bf16x8 af = *(const bf16x8*)&wb_h[(mt * 16 + l16) * 40 + q16 * 8];
        #pragma unroll
        for (int nt = 0; nt < 4; nt++) {
            const bf16x8 bf = *(const bf16x8*)&avaT_h[(nt * 16 + l16) * 40 + q16 * 8];
            f32x4 a = {0.f, 0.f, 0.f, 0.f};
            a = __builtin_amdgcn_mfma_f32_16x16x32_bf16(af, bf, a, 0, 0, 0);
            const int c = nt * 16 + l16, r0 = mt * 16 + q16 * 4;
            #pragma unroll
            for (int v = 0; v < 4; v++) {
                S32_h[(r0 + v) * 68 + c] = a[v];
                Sb_h[(r0 + v) * 72 + c]  = f2bf(a[v]);
            }
        }
    } else {
        const int mt = r - 2;
        #pragma unroll
        for (int nt = 0; nt < 4; nt++) {
            f32x4 a = {0.f, 0.f, 0.f, 0.f};
            #pragma unroll
            for (int ks = 0; ks < 2; ks++) {
                const bf16x8 af = *(const bf16x8*)&diffb_h[(mt * 16 + l16) * 72 + ks * 32 + q16 * 8];
                a = __builtin_amdgcn_mfma_f32_16x16x32_bf16(af, pwg[nt][ks], a, 0, 0, 0);
            }
            const int c = nt * 16 + l16, r0 = mt * 16 + q16 * 4;
            #pragma unroll
            for (int v = 0; v < 4; v++)
                DGf[hh * 2048 + (r0 + v) * 64 + c] = a[v];
        }
    }
    __syncthreads();

    // ---- phase D: dotSD (r=0) | sums (r=1) | SG (r=2,3)
    if (r == 0) {
        #pragma unroll
        for (int p = 0; p < 4; p++) {
            const int mt = p >> 1, nt = p & 1;
            f32x4 a = {0.f, 0.f, 0.f, 0.f};
            #pragma unroll
            for (int ks = 0; ks < 2; ks++) {
                const bf16x8 af = *(const bf16x8*)&Sb_h[(mt * 16 + l16) * 72 + ks * 32 + q16 * 8];
                const bf16x8 bf = *(const bf16x8*)&diffb_h[(nt * 16 + l16) * 72 + ks * 32 + q16 * 8];
                a = __builtin_amdgcn_mfma_f32_16x16x32_bf16(af, bf, a, 0, 0, 0);
            }
            const int j = nt * 16 + l16, r0 = mt * 16 + q16 * 4;
            #pragma unroll
            for (int v = 0; v < 4; v++)
                dotSD[((b * 4 + hh) * 32 + r0 + v) * 32 + j] = a[v];
        }
    } else if (r == 1) {
        if (e < 32) {       // sumS/sumS2 row e (fp32, same add order as before)
            float s1 = 0.f, s2 = 0.f;
            #pragma unroll
            for (int e4 = 0; e4 < 16; e4++) {
                const float4 v4 = *(const float4*)&S32_h[e * 68 + e4 * 4];
                s1 += v4.x + v4.y + v4.z + v4.w;
                s2 += v4.x * v4.x + v4.y * v4.y + v4.z * v4.z + v4.w * v4.w;
            }
            sumS[(b * 4 + hh) * 32 + e] = s1; sumS2[(b * 4 + hh) * 32 + e] = s2;
        } else {            // sumD/sumD2 row e-32 from bf16 diff
            const int rr = e - 32;
            float s1 = 0.f, s2 = 0.f;
            #pragma unroll
            for (int e8 = 0; e8 < 8; e8++) {
                const uint4 u = *(const uint4*)&diffb_h[rr * 72 + e8 * 8];
                const unsigned int uu[4] = {u.x, u.y, u.z, u.w};
                #pragma unroll
                for (int q = 0; q < 4; q++) {
                    const float fl = __uint_as_float(uu[q] << 16);
                    const float fh = __uint_as_float(uu[q] & 0xffff0000u);
                    s1 += fl + fh;
                    s2 += fl * fl + fh * fh;
                }
            }
            sumD[(b * 4 + hh) * 32 + rr] = s1; sumD2[(b * 4 + hh) * 32 + rr] = s2;
        }
    } else {
        const int mt = r - 2;
        #pragma unroll
        for (int nt = 0; nt < 4; nt++) {
            f32x4 a = {0.f, 0.f, 0.f, 0.f};
            #pragma unroll
            for (int ks = 0; ks < 2; ks++) {
                const bf16x8 af = *(const bf16x8*)&Sb_h[(mt * 16 + l16) * 72 + ks * 32 + q16 * 8];
                a = __builtin_amdgcn_mfma_f32_16x16x32_bf16(af, pwg[nt][ks], a, 0, 0, 0);
            }
            const int c = nt * 16 + l16, r0 = mt * 16 + q16 * 4;
            #pragma unroll
            for (int v = 0; v < 4; v++)
                SGF(hh)[(r0 + v) * 64 + c] = a[v];   // overlays dead avaT/wb
        }
    }
    __syncthreads();   // drains vmcnt(0): dotSD/sums/w_out visible below

    // ---- fused kC tail: wave w -> i-block ig=w>>2 (8 rows), j lanes w&3
    {
        const int ig = wave >> 2, w0 = wave & 3;
        const int i0 = ig * 8;
        const float bwr = BW[e];
        const float f2v = W_f2[e];
        float gw[4], sg[8][4];
        #pragma unroll
        for (int h4 = 0; h4 < 4; h4++) {
            gw[h4] = GW[h4 * 64 + e];
            #pragma unroll
            for (int ii = 0; ii < 8; ii++)
                sg[ii][h4] = SGF(h4)[(i0 + ii) * 64 + e];
        }
        // lane li=e&31 owns LN coeffs for (ii=li>>2, hh=li&3); lanes 32-63 dup
        const int rii  = (e & 31) >> 2;
        const int rhh  = e & 3;
        const int hi_r = (b * 4 + rhh) * 32 + i0 + rii;
        const float sSr  = sumS[hi_r];
        const float sS2r = sumS2[hi_r];

        for (int jg = 0; jg < 2; jg++) {
            for (int jb = 0; jb < 4; jb++) {
                const int j = jg * 16 + jb * 4 + w0;
                const int hj_r = (b * 4 + rhh) * 32 + j;
                const float wv  = w_out[hi_r * 32 + j];
                const float dsd = dotSD[hi_r * 32 + j];
                const float mu  = (sSr + wv * sumD[hj_r]) * (1.f / 64.f);
                const float e2  = (sS2r + 2.f * wv * dsd + wv * wv * sumD2[hj_r]) * (1.f / 64.f);
                const float var = fmaxf(e2 - mu * mu, 0.f);
                const float inv = rsqrtf(var + LN_EPS);
                const float ra = inv, rb = inv * wv, rc = -inv * mu;
                float d[4];
                #pragma unroll
                for (int h4 = 0; h4 < 4; h4++)
                    d[h4] = DGf[h4 * 2048 + j * 64 + e];
                #pragma unroll
                for (int ii = 0; ii < 8; ii++) {
                    float z = bwr;
                    #pragma unroll
                    for (int h4 = 0; h4 < 4; h4++) {
                        const int lane = ii * 4 + h4;
                        z += rdlane(ra, lane) * sg[ii][h4];
                        z += rdlane(rb, lane) * d[h4];
                        z += rdlane(rc, lane) * gw[h4];
                    }
                    float p = leaky(z) * f2v;
                    p = dppadd<0x111>(p);
                    p = dppadd<0x112>(p);
                    p = dppadd<0x114>(p);
                    p = dppadd<0x118>(p);
                    p = dppadd<0x142>(p);
                    p = dppadd<0x143>(p);
                    if (e == 63) value[(b * 32 + i0 + ii) * 32 + j] = p;
                }
            }
        }
    }
    #undef SGF
    #undef PHH
}

extern "C" void kernel_launch(void* const* d_in, const int* in_sizes, int n_in,
                              void* d_out, int out_size, void* d_ws, size_t ws_size,
                              hipStream_t stream)
{
    const float* states   = (const float*)d_in[0];
    const float* policies = (const float*)d_in[1];
    const float* actions  = (const float*)d_in[2];
    const float* W_se     = (const float*)d_in[3];
    const float* b_se     = (const float*)d_in[4];
    const float* W_sape   = (const float*)d_in[5];
    const float* b_sape   = (const float*)d_in[6];
    const float* Wk       = (const float*)d_in[7];
    const float* Wq       = (const float*)d_in[8];
    const float* Wv       = (const float*)d_in[9];
    const float* ln_g     = (const float*)d_in[10];
    const float* ln_b     = (const float*)d_in[11];
    const float* W_f1     = (const float*)d_in[12];
    const float* W_f2     = (const float*)d_in[13];

    float* out_value = (float*)d_out;
    float* out_w     = out_value + B * N * N;

    float* ws    = (float*)d_ws;
    float* SG    = ws;                       // unused (kept for layout stability)
    float* DG    = SG    + 1048576;          // unused
    float* sumS  = DG    + 1048576;          // 16,384
    float* sumS2 = sumS  + 16384;
    float* sumD  = sumS2 + 16384;
    float* sumD2 = sumD  + 16384;
    float* dotSD = sumD2 + 16384;            // 524,288
    float* GW    = dotSD + 524288;           // 256
    float* BW    = GW    + 256;              // 64
    u16*   wTb   = (u16*)(BW + 64);          // 98,304
    u16*   wseT  = wTb   + 98304;            // 16,384
    u16*   wsapeT= wseT  + 16384;            // 16,384
    u16*   sapeTail = wsapeT + 16384;        // 4,096
    u16*   wTg   = sapeTail + 4096;          // 16,384

    kP<<<7, 256, 0, stream>>>(Wk, Wq, Wv, W_se, W_sape, ln_g, ln_b, W_f1,
                              wTb, wseT, wsapeT, sapeTail, wTg, GW, BW);
    kB<<<B, 1024, 0, stream>>>(states, actions, policies, b_se, b_sape,
                               wTb, wseT, wsapeT, sapeTail, wTg, out_w,
                               sumS, sumS2, sumD, sumD2, dotSD,
                               GW, BW, W_f2, out_value);
}

// Round 5
// 125.031 us; speedup vs baseline: 1.1367x; 1.1367x over previous
//
#include <hip/hip_runtime.h>
#include <hip/hip_bf16.h>

#define B 128
#define N 32
#define DO 128
#define NA 16
#define H 4
#define DK 64
#define DV 64
#define LN_EPS 1e-5f
#define NEG_SLOPE 0.01f

typedef unsigned short u16;
typedef __attribute__((ext_vector_type(8))) short bf16x8;
typedef __attribute__((ext_vector_type(4))) float f32x4;

__device__ __forceinline__ float leaky(float x) {
    return x >= 0.f ? x : NEG_SLOPE * x;
}

__device__ __forceinline__ u16 f2bf(float x) {
    union { float f; unsigned int u; } v; v.f = x;
    unsigned int r = (v.u + 0x7FFF + ((v.u >> 16) & 1)) >> 16;
    return (u16)r;
}

__device__ __forceinline__ float bf2f(u16 x) {
    union { unsigned int u; float f; } v; v.u = ((unsigned int)x) << 16;
    return v.f;
}

// packed f32->bf16 RNE: 1 instr for 2 values (compiler can't derive from
// the bit-twiddle form). lo -> [15:0], hi -> [31:16].
__device__ __forceinline__ unsigned int cvtpk(float lo, float hi) {
    unsigned int r;
    asm("v_cvt_pk_bf16_f32 %0, %1, %2" : "=v"(r) : "v"(lo), "v"(hi));
    return r;
}

// DPP-based partial add: x += dpp_perm(x) on the VALU pipe.
template<int CTRL>
__device__ __forceinline__ float dppadd(float x) {
    return x + __int_as_float(__builtin_amdgcn_update_dpp(
        0, __float_as_int(x), CTRL, 0xF, 0xF, true));
}

// ---------------------------------------------------------------------------
// kP: one-shot weight prep — widened 7 -> 20 independent blocks (was a
// serial prelude on 7 CUs; block work split so each block does one slice).
//  blk 0-11 : Wq/Wk/Wv head hh=blk/3, matrix m=blk%3 -> wTb[(hh*3+m)*8192]
//  blk 12-13: W_se chunk 0/1 -> wseT
//  blk 14-15: W_sape chunk 0/1 -> wsapeT
//  blk 16   : W_sape rows 128-143 -> sapeTail (zero-pad)
//  blk 17-18: wTg half
//  blk 19   : GW fp32 + BW fp32
// ---------------------------------------------------------------------------
__global__ __launch_bounds__(256) void kP(
    const float* __restrict__ Wk, const float* __restrict__ Wq,
    const float* __restrict__ Wv, const float* __restrict__ W_se,
    const float* __restrict__ W_sape, const float* __restrict__ ln_g,
    const float* __restrict__ ln_b, const float* __restrict__ W_f1,
    u16* __restrict__ wTb, u16* __restrict__ wseT, u16* __restrict__ wsapeT,
    u16* __restrict__ sapeTail, u16* __restrict__ wTg,
    float* __restrict__ GW, float* __restrict__ BW)
{
    const int blk = blockIdx.x;
    const int t   = threadIdx.x;
    __shared__ float wls[8192];

    if (blk < 12) {
        const int hh = blk / 3, m = blk % 3;
        const float* src = (m == 0 ? Wq : (m == 1 ? Wk : Wv)) + hh * 8192;
        for (int idx = t; idx < 2048; idx += 256)
            ((float4*)wls)[idx] = ((const float4*)src)[idx];
        __syncthreads();
        u16* dst = wTb + (hh * 3 + m) * 8192;
        for (int idx = t; idx < 8192; idx += 256) {
            const int n = idx >> 7, k = idx & 127;
            dst[idx] = f2bf(wls[k * 64 + n]);
        }
    } else if (blk < 16) {
        const int which = (blk - 12) >> 1;      // 0: W_se, 1: W_sape
        const int chunk = blk & 1;
        const float* src = which ? W_sape : W_se;
        u16* dst = which ? wsapeT : wseT;
        const int k0 = chunk * 64;
        for (int idx = t; idx < 2048; idx += 256)
            ((float4*)wls)[idx] = ((const float4*)(src + k0 * 128))[idx];
        __syncthreads();
        for (int idx = t; idx < 8192; idx += 256) {
            const int n = idx >> 6, kk = idx & 63;
            dst[n * 128 + k0 + kk] = f2bf(wls[kk * 128 + n]);
        }
    } else if (blk == 16) {
        for (int idx = t; idx < 2048; idx += 256)
            wls[idx] = W_sape[128 * 128 + idx];
        __syncthreads();
        for (int idx = t; idx < 4096; idx += 256) {
            const int n = idx >> 5, kk = idx & 31;
            sapeTail[n * 32 + kk] = (kk < 16) ? f2bf(wls[kk * 128 + n]) : (u16)0;
        }
    } else if (blk <= 18) {
        const int base = (blk - 17) * 8192;
        for (int idx = t; idx < 8192; idx += 256) {
            const int g  = base + idx;
            const int hh = g >> 12, c = (g >> 6) & 63, ee = g & 63;
            wTg[g] = f2bf(ln_g[hh * 64 + ee] * W_f1[(hh * 64 + ee) * 64 + c]);
        }
    } else {
        {   // GW fp32-exact
            const int hh = t >> 6, c = t & 63;
            float g = 0.f;
            #pragma unroll 4
            for (int ee = 0; ee < 64; ee++)
                g += ln_g[hh * 64 + ee] * W_f1[(hh * 64 + ee) * 64 + c];
            GW[t] = g;
        }
        {   // BW fp32-exact via partials
            const int c = t & 63, qq = t >> 6;
            float bacc = 0.f;
            #pragma unroll 4
            for (int r = 0; r < 64; r++)
                bacc += ln_b[qq * 64 + r] * W_f1[(qq * 64 + r) * 64 + c];
            wls[qq * 64 + c] = bacc;
        }
        __syncthreads();
        if (t < 64) BW[t] = wls[t] + wls[64 + t] + wls[128 + t] + wls[192 + t];
    }
}

// ---------------------------------------------------------------------------
// Kernel B: 1024 threads; kA fused as phase -1 (se/xa/xp never hit global).
// Phases: stage | -1: se/xa/xp MFMA | A: q,k,ava,avp | B: softmax / diff |
//         C: S=w@ava + sumD / DG | D: dotSD / SG / sumS.  LDS 72,192B.
// R3: pre-barrier register prefetch of global MFMA B-operands.
// R5: all f2bf pairs -> v_cvt_pk_bf16_f32 (1 instr per 2 values; measured
// VALU-issue-bound at ~50% on busy CUs in R4's counters).
// ---------------------------------------------------------------------------
__global__ __launch_bounds__(1024, 8) void kB(
    const float* __restrict__ states, const float* __restrict__ actions,
    const float* __restrict__ policies,
    const float* __restrict__ b_se, const float* __restrict__ b_sape,
    const u16* __restrict__ wTb, const u16* __restrict__ wseT,
    const u16* __restrict__ wsapeT, const u16* __restrict__ sapeTail,
    const u16* __restrict__ wTg,
    float* __restrict__ w_out,
    float* __restrict__ SG, float* __restrict__ DG,
    float* __restrict__ sumS, float* __restrict__ sumS2,
    float* __restrict__ sumD, float* __restrict__ sumD2,
    float* __restrict__ dotSD)
{
    const int bh   = blockIdx.x;
    const int b    = bh >> 2;
    const int h    = bh & 3;
    const int t    = threadIdx.x;
    const int wave = t >> 6;
    const int e    = t & 63;
    const int q16  = e >> 4;
    const int l16  = e & 15;

    __shared__ alignas(16) u16   sST[32 * 136];
    __shared__ alignas(16) u16   actA[32 * 40];
    __shared__ alignas(16) u16   polA[32 * 40];
    __shared__ alignas(16) u16   sSE[32 * 136];
    __shared__ alignas(16) u16   sXA[32 * 136];
    __shared__ alignas(16) u16   sXP[32 * 136];
    __shared__ alignas(16) u16   qb[32 * 72];
    __shared__ alignas(16) u16   kb[32 * 72];
    __shared__ alignas(16) u16   avaT[64 * 40];
    __shared__ alignas(16) u16   diffb[32 * 72];
    __shared__ alignas(16) u16   wb[32 * 40];
    __shared__ alignas(16) float S32[32 * 68];
    __shared__ alignas(16) u16   Sb[32 * 72];

    // ---- prefetch phase -1 B-operands (no LDS dependency; issued at entry
    // so their latency hides under the stage + first barrier)
    const int mtP   = wave >> 3, ntP = wave & 7;
    const int bcolP = ntP * 16 + l16;
    bf16x8 pse[4];
    {
        const u16* bse_p = wseT + bcolP * 128;
        #pragma unroll
        for (int ks = 0; ks < 4; ks++)
            pse[ks] = *(const bf16x8*)&bse_p[ks * 32 + q16 * 8];
    }
    const bf16x8 btP   = *(const bf16x8*)&sapeTail[bcolP * 32 + q16 * 8];
    const float  bse_c = b_se[bcolP];
    const float  bsp_c = b_sape[bcolP];

    // ---- stage: states/actions/policies -> bf16 LDS
    {
        const int r = t >> 5, c4 = (t & 31) * 4;
        const float4 s4 = *(const float4*)&states[(b * 32 + r) * 128 + c4];
        uint2 u;
        u.x = cvtpk(s4.x, s4.y);
        u.y = cvtpk(s4.z, s4.w);
        *(uint2*)&sST[r * 136 + c4] = u;
    }
    if (t < 512) {
        const int r = t >> 4, c = t & 15;
        actA[r * 40 + c]      = f2bf(actions[(b * 32 + r) * 16 + c]);
        actA[r * 40 + 16 + c] = 0;
    } else {
        const int t2 = t - 512, r = t2 >> 4, c = t2 & 15;
        polA[r * 40 + c]      = f2bf(policies[(b * 32 + r) * 16 + c]);
        polA[r * 40 + 16 + c] = 0;
    }

    // second prefetch batch (issued pre-barrier; overlaps barrier wait)
    bf16x8 psp[4];
    {
        const u16* bsp_p = wsapeT + bcolP * 128;
        #pragma unroll
        for (int ks = 0; ks < 4; ks++)
            psp[ks] = *(const bf16x8*)&bsp_p[ks * 32 + q16 * 8];
    }
    __syncthreads();

    // ---- phase -1: se/xa/xp (wave = tile: mt=wave>>3, nt=wave&7)
    f32x4 acc[2];          // phase-A accumulators (declared early for scope)
    bf16x8 pw0[4];         // phase-A tile-0 weight prefetch
    {
        const int arow = mtP * 16 + l16;
        const int bcol = bcolP;
        f32x4 a_se = {0.f,0.f,0.f,0.f}, a_sp = {0.f,0.f,0.f,0.f};
        f32x4 a_oa = {0.f,0.f,0.f,0.f}, a_op = {0.f,0.f,0.f,0.f};
        #pragma unroll
        for (int ks = 0; ks < 4; ks++) {
            const bf16x8 af = *(const bf16x8*)&sST[arow * 136 + ks * 32 + q16 * 8];
            a_se = __builtin_amdgcn_mfma_f32_16x16x32_bf16(af, pse[ks], a_se, 0, 0, 0);
            a_sp = __builtin_amdgcn_mfma_f32_16x16x32_bf16(af, psp[ks], a_sp, 0, 0, 0);
        }
        a_oa = __builtin_amdgcn_mfma_f32_16x16x32_bf16(
            *(const bf16x8*)&actA[arow * 40 + q16 * 8], btP, a_oa, 0, 0, 0);
        a_op = __builtin_amdgcn_mfma_f32_16x16x32_bf16(
            *(const bf16x8*)&polA[arow * 40 + q16 * 8], btP, a_op, 0, 0, 0);

        // prefetch phase-A tile 0 weights while MFMAs drain (pse/psp now dead)
        {
            const int tau0 = wave * 2;
            const int mat0 = tau0 >> 3;
            const int widx0 = (mat0 == 0) ? 0 : (mat0 == 1 ? 1 : 2);
            const int nt0 = tau0 & 3;
            const u16* wsrc0 = wTb + ((h * 3 + widx0) * 64 + nt0 * 16 + l16) * 128;
            #pragma unroll
            for (int ks = 0; ks < 4; ks++)
                pw0[ks] = *(const bf16x8*)&wsrc0[ks * 32 + q16 * 8];
        }

        const int r0 = mtP * 16 + q16 * 4;
        #pragma unroll
        for (int v = 0; v < 4; v += 2) {
            const unsigned int use = cvtpk(leaky(a_se[v]     + bse_c),
                                           leaky(a_se[v + 1] + bse_c));
            const unsigned int uxa = cvtpk(leaky(a_sp[v]     + a_oa[v]     + bsp_c),
                                           leaky(a_sp[v + 1] + a_oa[v + 1] + bsp_c));
            const unsigned int uxp = cvtpk(leaky(a_sp[v]     + a_op[v]     + bsp_c),
                                           leaky(a_sp[v + 1] + a_op[v + 1] + bsp_c));
            sSE[(r0 + v) * 136 + bcol]     = (u16)use;
            sSE[(r0 + v + 1) * 136 + bcol] = (u16)(use >> 16);
            sXA[(r0 + v) * 136 + bcol]     = (u16)uxa;
            sXA[(r0 + v + 1) * 136 + bcol] = (u16)(uxa >> 16);
            sXP[(r0 + v) * 136 + bcol]     = (u16)uxp;
            sXP[(r0 + v + 1) * 136 + bcol] = (u16)(uxp >> 16);
        }
    }
    __syncthreads();

    // ---- phase A: q,k,ava,avp — 2 tiles/wave, K=128 (tile 0 weights in regs)
    #pragma unroll
    for (int p = 0; p < 2; p++) {
        const int tau = wave * 2 + p;
        const int mat = tau >> 3;
        const int mt  = (tau >> 2) & 1, nt = tau & 3;
        const u16* X  = (mat <= 1) ? sSE : (mat == 2 ? sXA : sXP);
        const int widx = (mat == 0) ? 0 : (mat == 1 ? 1 : 2);
        const int arow = mt * 16 + l16;
        const u16* wsrc = wTb + ((h * 3 + widx) * 64 + nt * 16 + l16) * 128;
        f32x4 a = {0.f, 0.f, 0.f, 0.f};
        #pragma unroll
        for (int ks = 0; ks < 4; ks++) {
            const bf16x8 af = *(const bf16x8*)&X[arow * 136 + ks * 32 + q16 * 8];
            const bf16x8 bf = (p == 0) ? pw0[ks]
                                       : *(const bf16x8*)&wsrc[ks * 32 + q16 * 8];
            a = __builtin_amdgcn_mfma_f32_16x16x32_bf16(af, bf, a, 0, 0, 0);
        }
        acc[p] = a;
    }
    #pragma unroll
    for (int p = 0; p < 2; p++) {
        const int tau = wave * 2 + p;
        const int mat = tau >> 3;
        const int mt  = (tau >> 2) & 1, nt = tau & 3;
        const int c   = nt * 16 + l16;
        const int r0  = mt * 16 + q16 * 4;
        if (mat == 0) {
            #pragma unroll
            for (int v = 0; v < 4; v += 2) {
                const unsigned int u = cvtpk(acc[p][v], acc[p][v + 1]);
                qb[(r0 + v) * 72 + c]     = (u16)u;
                qb[(r0 + v + 1) * 72 + c] = (u16)(u >> 16);
            }
        } else if (mat == 1) {
            #pragma unroll
            for (int v = 0; v < 4; v += 2) {
                const unsigned int u = cvtpk(acc[p][v], acc[p][v + 1]);
                kb[(r0 + v) * 72 + c]     = (u16)u;
                kb[(r0 + v + 1) * 72 + c] = (u16)(u >> 16);
            }
        } else if (mat == 2) {
            // v-adjacent in avaT: 2 values per ds_write_b32
            *(unsigned int*)&avaT[c * 40 + r0]     = cvtpk(acc[p][0], acc[p][1]);
            *(unsigned int*)&avaT[c * 40 + r0 + 2] = cvtpk(acc[p][2], acc[p][3]);
        } // mat==3 (avp) held in regs
    }
    __syncthreads();

    // ---- phase B: scores+softmax (waves 0-1) | diff (waves 12-15)
    //      waves 8-15 additionally prefetch their wTg fragments (used in BOTH
    //      phase C and phase D — same nt per wave, so one load serves both)
    bf16x8 pwg[2];
    if (wave >= 8) {
        const int nt = (wave - 8) & 3;
        const u16* wgp = wTg + (h * 64 + nt * 16 + l16) * 64;
        #pragma unroll
        for (int ks = 0; ks < 2; ks++)
            pwg[ks] = *(const bf16x8*)&wgp[ks * 32 + q16 * 8];
    }
    if (wave < 2) {
        const int mt = wave;
        f32x4 s0 = {0.f,0.f,0.f,0.f}, s1 = {0.f,0.f,0.f,0.f};
        #pragma unroll
        for (int ks = 0; ks < 2; ks++) {
            const bf16x8 af = *(const bf16x8*)&qb[(mt * 16 + l16) * 72 + ks * 32 + q16 * 8];
            const bf16x8 b0 = *(const bf16x8*)&kb[l16 * 72 + ks * 32 + q16 * 8];
            const bf16x8 b1 = *(const bf16x8*)&kb[(16 + l16) * 72 + ks * 32 + q16 * 8];
            s0 = __builtin_amdgcn_mfma_f32_16x16x32_bf16(af, b0, s0, 0, 0, 0);
            s1 = __builtin_amdgcn_mfma_f32_16x16x32_bf16(af, b1, s1, 0, 0, 0);
        }
        #pragma unroll
        for (int v = 0; v < 4; v++) {
            float a0 = s0[v] * 0.125f, a1 = s1[v] * 0.125f;
            float mx = fmaxf(a0, a1);
            #pragma unroll
            for (int m = 1; m < 16; m <<= 1) mx = fmaxf(mx, __shfl_xor(mx, m));
            float e0 = __expf(a0 - mx), e1 = __expf(a1 - mx);
            float sm = e0 + e1;
            #pragma unroll
            for (int m = 1; m < 16; m <<= 1) sm += __shfl_xor(sm, m);
            const float inv = 1.f / sm;
            e0 *= inv; e1 *= inv;
            const int i = mt * 16 + q16 * 4 + v;
            const unsigned int uw = cvtpk(e0, e1);
            wb[i * 40 + l16]      = (u16)uw;
            wb[i * 40 + 16 + l16] = (u16)(uw >> 16);
            w_out[(bh * 32 + i) * 32 + l16]      = e0;
            w_out[(bh * 32 + i) * 32 + 16 + l16] = e1;
        }
    } else if (wave >= 12) {
        #pragma unroll
        for (int p = 0; p < 2; p++) {
            const int tau = wave * 2 + p;
            const int mt  = (tau >> 2) & 1, nt = tau & 3;
            const int c   = nt * 16 + l16;
            const int r0  = mt * 16 + q16 * 4;
            #pragma unroll
            for (int v = 0; v < 4; v += 2) {
                const float av0 = bf2f(avaT[c * 40 + (r0 + v)]);
                const float av1 = bf2f(avaT[c * 40 + (r0 + v + 1)]);
                const unsigned int u = cvtpk(acc[p][v] - av0, acc[p][v + 1] - av1);
                diffb[(r0 + v) * 72 + c]     = (u16)u;
                diffb[(r0 + v + 1) * 72 + c] = (u16)(u >> 16);
            }
        }
    }
    __syncthreads();

    // ---- phase C: S = w@ava (waves 0-7) | DG = diff@Wg (waves 8-15)
    if (wave < 8) {
        const int mt = wave >> 2, nt = wave & 3;
        const bf16x8 af = *(const bf16x8*)&wb[(mt * 16 + l16) * 40 + q16 * 8];
        const bf16x8 bf = *(const bf16x8*)&avaT[(nt * 16 + l16) * 40 + q16 * 8];
        f32x4 a = {0.f, 0.f, 0.f, 0.f};
        a = __builtin_amdgcn_mfma_f32_16x16x32_bf16(af, bf, a, 0, 0, 0);
        const int c = nt * 16 + l16, r0 = mt * 16 + q16 * 4;
        #pragma unroll
        for (int v = 0; v < 4; v += 2) {
            S32[(r0 + v) * 68 + c]     = a[v];
            S32[(r0 + v + 1) * 68 + c] = a[v + 1];
            const unsigned int u = cvtpk(a[v], a[v + 1]);
            Sb[(r0 + v) * 72 + c]     = (u16)u;
            Sb[(r0 + v + 1) * 72 + c] = (u16)(u >> 16);
        }
    } else {
        const int w8 = wave - 8;
        const int mt = w8 >> 2, nt = w8 & 3;
        f32x4 a = {0.f, 0.f, 0.f, 0.f};
        #pragma unroll
        for (int ks = 0; ks < 2; ks++) {
            const bf16x8 af = *(const bf16x8*)&diffb[(mt * 16 + l16) * 72 + ks * 32 + q16 * 8];
            a = __builtin_amdgcn_mfma_f32_16x16x32_bf16(af, pwg[ks], a, 0, 0, 0);
        }
        const int c = nt * 16 + l16, r0 = mt * 16 + q16 * 4;
        #pragma unroll
        for (int v = 0; v < 4; v++)
            DG[(bh * 32 + r0 + v) * 64 + c] = a[v];
    }
    if (t < 32) {   // sumD/sumD2 from bf16 diff (fp32 accum)
        float s1 = 0.f, s2 = 0.f;
        #pragma unroll
        for (int e8 = 0; e8 < 8; e8++) {
            const uint4 u = *(const uint4*)&diffb[t * 72 + e8 * 8];
            const unsigned int uu[4] = {u.x, u.y, u.z, u.w};
            #pragma unroll
            for (int q = 0; q < 4; q++) {
                const float fl = __uint_as_float(uu[q] << 16);
                const float fh = __uint_as_float(uu[q] & 0xffff0000u);
                s1 += fl + fh;
                s2 += fl * fl + fh * fh;
            }
        }
        sumD[bh * 32 + t] = s1; sumD2[bh * 32 + t] = s2;
    }
    __syncthreads();

    // ---- phase D: dotSD (waves 0-3) | SG (waves 8-15) | sumS (t in [256,288))
    if (wave < 4) {
        const int mt = wave >> 1, nt = wave & 1;
        f32x4 a = {0.f, 0.f, 0.f, 0.f};
        #pragma unroll
        for (int ks = 0; ks < 2; ks++) {
            const bf16x8 af = *(const bf16x8*)&Sb[(mt * 16 + l16) * 72 + ks * 32 + q16 * 8];
            const bf16x8 bf = *(const bf16x8*)&diffb[(nt * 16 + l16) * 72 + ks * 32 + q16 * 8];
            a = __builtin_amdgcn_mfma_f32_16x16x32_bf16(af, bf, a, 0, 0, 0);
        }
        const int j = nt * 16 + l16, r0 = mt * 16 + q16 * 4;
        #pragma unroll
        for (int v = 0; v < 4; v++)
            dotSD[(bh * 32 + r0 + v) * 32 + j] = a[v];
    } else if (wave >= 8) {
        const int w8 = wave - 8;
        const int mt = w8 >> 2, nt = w8 & 3;
        f32x4 a = {0.f, 0.f, 0.f, 0.f};
        #pragma unroll
        for (int ks = 0; ks < 2; ks++) {
            const bf16x8 af = *(const bf16x8*)&Sb[(mt * 16 + l16) * 72 + ks * 32 + q16 * 8];
            a = __builtin_amdgcn_mfma_f32_16x16x32_bf16(af, pwg[ks], a, 0, 0, 0);
        }
        const int c = nt * 16 + l16, r0 = mt * 16 + q16 * 4;
        #pragma unroll
        for (int v = 0; v < 4; v++)
            SG[(bh * 32 + r0 + v) * 64 + c] = a[v];
    } else if (t >= 256 && t < 288) {
        const int r = t - 256;
        float s1 = 0.f, s2 = 0.f;
        #pragma unroll
        for (int e4 = 0; e4 < 16; e4++) {
            const float4 v4 = *(const float4*)&S32[r * 68 + e4 * 4];
            s1 += v4.x + v4.y + v4.z + v4.w;
            s2 += v4.x * v4.x + v4.y * v4.y + v4.z * v4.z + v4.w * v4.w;
        }
        sumS[bh * 32 + r] = s1; sumS2[bh * 32 + r] = s2;
    }
}

// ---------------------------------------------------------------------------
// Kernel C (1024 blocks: b x 4 i-groups x 2 j-groups; 256 threads).
// LDS-lean: per-(ii,j) LN coefficients packed as 12-float records -> 3
// uniform ds_read_b128 per tile; SG/GW/BW/W_f2 in registers; DPP reduce.
// ---------------------------------------------------------------------------
__global__ __launch_bounds__(256) void kC(
    const float* __restrict__ SG, const float* __restrict__ DG,
    const float* __restrict__ sumS, const float* __restrict__ sumS2,
    const float* __restrict__ sumD, const float* __restrict__ sumD2,
    const float* __restrict__ dotSD, const float* __restrict__ w_all,
    const float* __restrict__ GW, const float* __restrict__ BW,
    const float* __restrict__ W_f2, float* __restrict__ value)
{
    const int blk = blockIdx.x;          // b*8 + ig*2 + jg
    const int b   = blk >> 3;
    const int i0  = ((blk >> 1) & 3) * 8;
    const int j0  = (blk & 1) * 16;
    const int t   = threadIdx.x;
    const int w0  = t >> 6;              // 0..3
    const int e   = t & 63;

    __shared__ alignas(16) float pk[8 * 16 * 12];   // [ii][jl][hh*3 + {a,b,c}]

    // per-(ii,jl,hh) LN coefficients: a=inv, b=inv*w, c=-inv*mu
    for (int idx = t; idx < 512; idx += 256) {
        const int ii = idx >> 6, jl = (idx >> 2) & 15, hh = idx & 3;
        const int j  = j0 + jl;
        const int hi = (b * 4 + hh) * 32 + i0 + ii;
        const int hj = (b * 4 + hh) * 32 + j;
        const float wv  = w_all[hi * 32 + j];
        const float dsd = dotSD[hi * 32 + j];
        const float mu  = (sumS[hi] + wv * sumD[hj]) * (1.f / 64.f);
        const float e2  = (sumS2[hi] + 2.f * wv * dsd + wv * wv * sumD2[hj]) * (1.f / 64.f);
        const float var = fmaxf(e2 - mu * mu, 0.f);
        const float inv = rsqrtf(var + LN_EPS);
        float* rec = &pk[(ii * 16 + jl) * 12 + hh * 3];
        rec[0] = inv;
        rec[1] = inv * wv;
        rec[2] = -inv * mu;
    }

    // register-resident row data (independent of pk; loads overlap the sync)
    const float bwr = BW[e];
    const float f2v = W_f2[e];
    float gw[4], sg[8][4];
    #pragma unroll
    for (int hh = 0; hh < 4; hh++) {
        gw[hh] = GW[hh * 64 + e];
        #pragma unroll
        for (int ii = 0; ii < 8; ii++)
            sg[ii][hh] = SG[((b * 4 + hh) * 32 + i0 + ii) * 64 + e];
    }
    __syncthreads();

    for (int jb = 0; jb < 4; jb++) {
        const int jl = jb * 4 + w0;      // 0..15, wave-uniform
        const int j  = j0 + jl;
        float d[4];
        #pragma unroll
        for (int hh = 0; hh < 4; hh++)
            d[hh] = DG[((b * 4 + hh) * 32 + j) * 64 + e];
        #pragma unroll
        for (int ii = 0; ii < 8; ii++) {
            const float* rec = &pk[(ii * 16 + jl) * 12];
            const f32x4 r0 = *(const f32x4*)rec;         // a0 b0 c0 a1
            const f32x4 r1 = *(const f32x4*)(rec + 4);   // b1 c1 a2 b2
            const f32x4 r2 = *(const f32x4*)(rec + 8);   // c2 a3 b3 c3
            float z = bwr;
            z += r0[0] * sg[ii][0]; z += r0[1] * d[0]; z += r0[2] * gw[0];
            z += r0[3] * sg[ii][1]; z += r1[0] * d[1]; z += r1[1] * gw[1];
            z += r1[2] * sg[ii][2]; z += r1[3] * d[2]; z += r2[0] * gw[2];
            z += r2[1] * sg[ii][3]; z += r2[2] * d[3]; z += r2[3] * gw[3];
            float p = leaky(z) * f2v;
            // 64-lane sum on the VALU pipe: row_shr 1/2/4/8 then bcast15/31;
            // lane 63 ends with the full sum.
            p = dppadd<0x111>(p);
            p = dppadd<0x112>(p);
            p = dppadd<0x114>(p);
            p = dppadd<0x118>(p);
            p = dppadd<0x142>(p);
            p = dppadd<0x143>(p);
            if (e == 63) value[(b * 32 + i0 + ii) * 32 + j] = p;
        }
    }
}

extern "C" void kernel_launch(void* const* d_in, const int* in_sizes, int n_in,
                              void* d_out, int out_size, void* d_ws, size_t ws_size,
                              hipStream_t stream)
{
    const float* states   = (const float*)d_in[0];
    const float* policies = (const float*)d_in[1];
    const float* actions  = (const float*)d_in[2];
    const float* W_se     = (const float*)d_in[3];
    const float* b_se     = (const float*)d_in[4];
    const float* W_sape   = (const float*)d_in[5];
    const float* b_sape   = (const float*)d_in[6];
    const float* Wk       = (const float*)d_in[7];
    const float* Wq       = (const float*)d_in[8];
    const float* Wv       = (const float*)d_in[9];
    const float* ln_g     = (const float*)d_in[10];
    const float* ln_b     = (const float*)d_in[11];
    const float* W_f1     = (const float*)d_in[12];
    const float* W_f2     = (const float*)d_in[13];

    float* out_value = (float*)d_out;
    float* out_w     = out_value + B * N * N;

    float* ws    = (float*)d_ws;
    float* SG    = ws;                       // 1,048,576
    float* DG    = SG    + 1048576;          // 1,048,576
    float* sumS  = DG    + 1048576;          // 16,384
    float* sumS2 = sumS  + 16384;
    float* sumD  = sumS2 + 16384;
    float* sumD2 = sumD  + 16384;
    float* dotSD = sumD2 + 16384;            // 524,288
    float* GW    = dotSD + 524288;           // 256
    float* BW    = GW    + 256;              // 64
    u16*   wTb   = (u16*)(BW + 64);          // 98,304
    u16*   wseT  = wTb   + 98304;            // 16,384
    u16*   wsapeT= wseT  + 16384;            // 16,384
    u16*   sapeTail = wsapeT + 16384;        // 4,096
    u16*   wTg   = sapeTail + 4096;          // 16,384

    kP<<<20, 256, 0, stream>>>(Wk, Wq, Wv, W_se, W_sape, ln_g, ln_b, W_f1,
                               wTb, wseT, wsapeT, sapeTail, wTg, GW, BW);
    kB<<<B * H, 1024, 0, stream>>>(states, actions, policies, b_se, b_sape,
                                   wTb, wseT, wsapeT, sapeTail, wTg, out_w,
                                   SG, DG, sumS, sumS2, sumD, sumD2, dotSD);
    kC<<<B * 8, 256, 0, stream>>>(SG, DG, sumS, sumS2, sumD, sumD2, dotSD,
                                  out_w, GW, BW, W_f2, out_value);
}

// Round 6
// 122.564 us; speedup vs baseline: 1.1596x; 1.0201x over previous
//
#include <hip/hip_runtime.h>
#include <hip/hip_bf16.h>

#define B 128
#define N 32
#define DO 128
#define NA 16
#define H 4
#define DK 64
#define DV 64
#define LN_EPS 1e-5f
#define NEG_SLOPE 0.01f

typedef unsigned short u16;
typedef __attribute__((ext_vector_type(8))) short bf16x8;
typedef __attribute__((ext_vector_type(4))) float f32x4;

__device__ __forceinline__ float leaky(float x) {
    return x >= 0.f ? x : NEG_SLOPE * x;
}

__device__ __forceinline__ u16 f2bf(float x) {
    union { float f; unsigned int u; } v; v.f = x;
    unsigned int r = (v.u + 0x7FFF + ((v.u >> 16) & 1)) >> 16;
    return (u16)r;
}

__device__ __forceinline__ float bf2f(u16 x) {
    union { unsigned int u; float f; } v; v.u = ((unsigned int)x) << 16;
    return v.f;
}

// packed f32->bf16 RNE: 1 instr for 2 values.
__device__ __forceinline__ unsigned int cvtpk(float lo, float hi) {
    unsigned int r;
    asm("v_cvt_pk_bf16_f32 %0, %1, %2" : "=v"(r) : "v"(lo), "v"(hi));
    return r;
}

// DPP partial ops on the VALU pipe (vs __shfl_xor -> ds_bpermute on LDS pipe).
template<int CTRL>
__device__ __forceinline__ float dppadd(float x) {
    return x + __int_as_float(__builtin_amdgcn_update_dpp(
        0, __float_as_int(x), CTRL, 0xF, 0xF, true));
}
template<int CTRL>
__device__ __forceinline__ float dppmax(float x) {
    return fmaxf(x, __int_as_float(__builtin_amdgcn_update_dpp(
        0, __float_as_int(x), CTRL, 0xF, 0xF, true)));
}
// row_ror:N ctrl encodings (16-lane rows)
#define ROR1 0x121
#define ROR2 0x122
#define ROR4 0x124
#define ROR8 0x128

// ---------------------------------------------------------------------------
// kP: one-shot weight prep — 20 independent blocks (parallel prelude).
// ---------------------------------------------------------------------------
__global__ __launch_bounds__(256) void kP(
    const float* __restrict__ Wk, const float* __restrict__ Wq,
    const float* __restrict__ Wv, const float* __restrict__ W_se,
    const float* __restrict__ W_sape, const float* __restrict__ ln_g,
    const float* __restrict__ ln_b, const float* __restrict__ W_f1,
    u16* __restrict__ wTb, u16* __restrict__ wseT, u16* __restrict__ wsapeT,
    u16* __restrict__ sapeTail, u16* __restrict__ wTg,
    float* __restrict__ GW, float* __restrict__ BW)
{
    const int blk = blockIdx.x;
    const int t   = threadIdx.x;
    __shared__ float wls[8192];

    if (blk < 12) {
        const int hh = blk / 3, m = blk % 3;
        const float* src = (m == 0 ? Wq : (m == 1 ? Wk : Wv)) + hh * 8192;
        for (int idx = t; idx < 2048; idx += 256)
            ((float4*)wls)[idx] = ((const float4*)src)[idx];
        __syncthreads();
        u16* dst = wTb + (hh * 3 + m) * 8192;
        for (int idx = t; idx < 8192; idx += 256) {
            const int n = idx >> 7, k = idx & 127;
            dst[idx] = f2bf(wls[k * 64 + n]);
        }
    } else if (blk < 16) {
        const int which = (blk - 12) >> 1;      // 0: W_se, 1: W_sape
        const int chunk = blk & 1;
        const float* src = which ? W_sape : W_se;
        u16* dst = which ? wsapeT : wseT;
        const int k0 = chunk * 64;
        for (int idx = t; idx < 2048; idx += 256)
            ((float4*)wls)[idx] = ((const float4*)(src + k0 * 128))[idx];
        __syncthreads();
        for (int idx = t; idx < 8192; idx += 256) {
            const int n = idx >> 6, kk = idx & 63;
            dst[n * 128 + k0 + kk] = f2bf(wls[kk * 128 + n]);
        }
    } else if (blk == 16) {
        for (int idx = t; idx < 2048; idx += 256)
            wls[idx] = W_sape[128 * 128 + idx];
        __syncthreads();
        for (int idx = t; idx < 4096; idx += 256) {
            const int n = idx >> 5, kk = idx & 31;
            sapeTail[n * 32 + kk] = (kk < 16) ? f2bf(wls[kk * 128 + n]) : (u16)0;
        }
    } else if (blk <= 18) {
        const int base = (blk - 17) * 8192;
        for (int idx = t; idx < 8192; idx += 256) {
            const int g  = base + idx;
            const int hh = g >> 12, c = (g >> 6) & 63, ee = g & 63;
            wTg[g] = f2bf(ln_g[hh * 64 + ee] * W_f1[(hh * 64 + ee) * 64 + c]);
        }
    } else {
        {   // GW fp32-exact
            const int hh = t >> 6, c = t & 63;
            float g = 0.f;
            #pragma unroll 4
            for (int ee = 0; ee < 64; ee++)
                g += ln_g[hh * 64 + ee] * W_f1[(hh * 64 + ee) * 64 + c];
            GW[t] = g;
        }
        {   // BW fp32-exact via partials
            const int c = t & 63, qq = t >> 6;
            float bacc = 0.f;
            #pragma unroll 4
            for (int r = 0; r < 64; r++)
                bacc += ln_b[qq * 64 + r] * W_f1[(qq * 64 + r) * 64 + c];
            wls[qq * 64 + c] = bacc;
        }
        __syncthreads();
        if (t < 64) BW[t] = wls[t] + wls[64 + t] + wls[128 + t] + wls[192 + t];
    }
}

// ---------------------------------------------------------------------------
// Kernel B: 1024 threads; kA fused as phase -1.
// R6 critical-path fixes (all barrier-drain / serial-chain, no math changes):
//  - w_out + DG global stores deferred past the LAST barrier (regs), sumD
//    moved from phase C (busy wave 0) to phase D (idle wave 5): every
//    mid-kernel __syncthreads now drains only LDS, not vmcnt store-ACKs.
//  - softmax 16-lane reductions: __shfl_xor (ds_bpermute, serial ~100cyc
//    each on LDS pipe) -> DPP row_ror rotate-reduce (VALU pipe).
// ---------------------------------------------------------------------------
__global__ __launch_bounds__(1024, 8) void kB(
    const float* __restrict__ states, const float* __restrict__ actions,
    const float* __restrict__ policies,
    const float* __restrict__ b_se, const float* __restrict__ b_sape,
    const u16* __restrict__ wTb, const u16* __restrict__ wseT,
    const u16* __restrict__ wsapeT, const u16* __restrict__ sapeTail,
    const u16* __restrict__ wTg,
    float* __restrict__ w_out,
    float* __restrict__ SG, float* __restrict__ DG,
    float* __restrict__ sumS, float* __restrict__ sumS2,
    float* __restrict__ sumD, float* __restrict__ sumD2,
    float* __restrict__ dotSD)
{
    const int bh   = blockIdx.x;
    const int b    = bh >> 2;
    const int h    = bh & 3;
    const int t    = threadIdx.x;
    const int wave = t >> 6;
    const int e    = t & 63;
    const int q16  = e >> 4;
    const int l16  = e & 15;

    __shared__ alignas(16) u16   sST[32 * 136];
    __shared__ alignas(16) u16   actA[32 * 40];
    __shared__ alignas(16) u16   polA[32 * 40];
    __shared__ alignas(16) u16   sSE[32 * 136];
    __shared__ alignas(16) u16   sXA[32 * 136];
    __shared__ alignas(16) u16   sXP[32 * 136];
    __shared__ alignas(16) u16   qb[32 * 72];
    __shared__ alignas(16) u16   kb[32 * 72];
    __shared__ alignas(16) u16   avaT[64 * 40];
    __shared__ alignas(16) u16   diffb[32 * 72];
    __shared__ alignas(16) u16   wb[32 * 40];
    __shared__ alignas(16) float S32[32 * 68];
    __shared__ alignas(16) u16   Sb[32 * 72];

    // deferred-store registers
    float  wo[8];        // waves 0-1: softmax outputs (e0,e1 per v)
    f32x4  dg_a;         // waves 8-15: DG tile

    // ---- prefetch phase -1 B-operands
    const int mtP   = wave >> 3, ntP = wave & 7;
    const int bcolP = ntP * 16 + l16;
    bf16x8 pse[4];
    {
        const u16* bse_p = wseT + bcolP * 128;
        #pragma unroll
        for (int ks = 0; ks < 4; ks++)
            pse[ks] = *(const bf16x8*)&bse_p[ks * 32 + q16 * 8];
    }
    const bf16x8 btP   = *(const bf16x8*)&sapeTail[bcolP * 32 + q16 * 8];
    const float  bse_c = b_se[bcolP];
    const float  bsp_c = b_sape[bcolP];

    // ---- stage: states/actions/policies -> bf16 LDS
    {
        const int r = t >> 5, c4 = (t & 31) * 4;
        const float4 s4 = *(const float4*)&states[(b * 32 + r) * 128 + c4];
        uint2 u;
        u.x = cvtpk(s4.x, s4.y);
        u.y = cvtpk(s4.z, s4.w);
        *(uint2*)&sST[r * 136 + c4] = u;
    }
    if (t < 512) {
        const int r = t >> 4, c = t & 15;
        actA[r * 40 + c]      = f2bf(actions[(b * 32 + r) * 16 + c]);
        actA[r * 40 + 16 + c] = 0;
    } else {
        const int t2 = t - 512, r = t2 >> 4, c = t2 & 15;
        polA[r * 40 + c]      = f2bf(policies[(b * 32 + r) * 16 + c]);
        polA[r * 40 + 16 + c] = 0;
    }

    bf16x8 psp[4];
    {
        const u16* bsp_p = wsapeT + bcolP * 128;
        #pragma unroll
        for (int ks = 0; ks < 4; ks++)
            psp[ks] = *(const bf16x8*)&bsp_p[ks * 32 + q16 * 8];
    }
    __syncthreads();

    // ---- phase -1: se/xa/xp (wave = tile: mt=wave>>3, nt=wave&7)
    f32x4 acc[2];
    bf16x8 pw0[4];
    {
        const int arow = mtP * 16 + l16;
        const int bcol = bcolP;
        f32x4 a_se = {0.f,0.f,0.f,0.f}, a_sp = {0.f,0.f,0.f,0.f};
        f32x4 a_oa = {0.f,0.f,0.f,0.f}, a_op = {0.f,0.f,0.f,0.f};
        #pragma unroll
        for (int ks = 0; ks < 4; ks++) {
            const bf16x8 af = *(const bf16x8*)&sST[arow * 136 + ks * 32 + q16 * 8];
            a_se = __builtin_amdgcn_mfma_f32_16x16x32_bf16(af, pse[ks], a_se, 0, 0, 0);
            a_sp = __builtin_amdgcn_mfma_f32_16x16x32_bf16(af, psp[ks], a_sp, 0, 0, 0);
        }
        a_oa = __builtin_amdgcn_mfma_f32_16x16x32_bf16(
            *(const bf16x8*)&actA[arow * 40 + q16 * 8], btP, a_oa, 0, 0, 0);
        a_op = __builtin_amdgcn_mfma_f32_16x16x32_bf16(
            *(const bf16x8*)&polA[arow * 40 + q16 * 8], btP, a_op, 0, 0, 0);

        // prefetch phase-A tile 0 weights while MFMAs drain
        {
            const int tau0 = wave * 2;
            const int mat0 = tau0 >> 3;
            const int widx0 = (mat0 == 0) ? 0 : (mat0 == 1 ? 1 : 2);
            const int nt0 = tau0 & 3;
            const u16* wsrc0 = wTb + ((h * 3 + widx0) * 64 + nt0 * 16 + l16) * 128;
            #pragma unroll
            for (int ks = 0; ks < 4; ks++)
                pw0[ks] = *(const bf16x8*)&wsrc0[ks * 32 + q16 * 8];
        }

        const int r0 = mtP * 16 + q16 * 4;
        #pragma unroll
        for (int v = 0; v < 4; v += 2) {
            const unsigned int use = cvtpk(leaky(a_se[v]     + bse_c),
                                           leaky(a_se[v + 1] + bse_c));
            const unsigned int uxa = cvtpk(leaky(a_sp[v]     + a_oa[v]     + bsp_c),
                                           leaky(a_sp[v + 1] + a_oa[v + 1] + bsp_c));
            const unsigned int uxp = cvtpk(leaky(a_sp[v]     + a_op[v]     + bsp_c),
                                           leaky(a_sp[v + 1] + a_op[v + 1] + bsp_c));
            sSE[(r0 + v) * 136 + bcol]     = (u16)use;
            sSE[(r0 + v + 1) * 136 + bcol] = (u16)(use >> 16);
            sXA[(r0 + v) * 136 + bcol]     = (u16)uxa;
            sXA[(r0 + v + 1) * 136 + bcol] = (u16)(uxa >> 16);
            sXP[(r0 + v) * 136 + bcol]     = (u16)uxp;
            sXP[(r0 + v + 1) * 136 + bcol] = (u16)(uxp >> 16);
        }
    }
    __syncthreads();

    // ---- phase A: q,k,ava,avp — 2 tiles/wave, K=128
    #pragma unroll
    for (int p = 0; p < 2; p++) {
        const int tau = wave * 2 + p;
        const int mat = tau >> 3;
        const int mt  = (tau >> 2) & 1, nt = tau & 3;
        const u16* X  = (mat <= 1) ? sSE : (mat == 2 ? sXA : sXP);
        const int widx = (mat == 0) ? 0 : (mat == 1 ? 1 : 2);
        const int arow = mt * 16 + l16;
        const u16* wsrc = wTb + ((h * 3 + widx) * 64 + nt * 16 + l16) * 128;
        f32x4 a = {0.f, 0.f, 0.f, 0.f};
        #pragma unroll
        for (int ks = 0; ks < 4; ks++) {
            const bf16x8 af = *(const bf16x8*)&X[arow * 136 + ks * 32 + q16 * 8];
            const bf16x8 bf = (p == 0) ? pw0[ks]
                                       : *(const bf16x8*)&wsrc[ks * 32 + q16 * 8];
            a = __builtin_amdgcn_mfma_f32_16x16x32_bf16(af, bf, a, 0, 0, 0);
        }
        acc[p] = a;
    }
    #pragma unroll
    for (int p = 0; p < 2; p++) {
        const int tau = wave * 2 + p;
        const int mat = tau >> 3;
        const int mt  = (tau >> 2) & 1, nt = tau & 3;
        const int c   = nt * 16 + l16;
        const int r0  = mt * 16 + q16 * 4;
        if (mat == 0) {
            #pragma unroll
            for (int v = 0; v < 4; v += 2) {
                const unsigned int u = cvtpk(acc[p][v], acc[p][v + 1]);
                qb[(r0 + v) * 72 + c]     = (u16)u;
                qb[(r0 + v + 1) * 72 + c] = (u16)(u >> 16);
            }
        } else if (mat == 1) {
            #pragma unroll
            for (int v = 0; v < 4; v += 2) {
                const unsigned int u = cvtpk(acc[p][v], acc[p][v + 1]);
                kb[(r0 + v) * 72 + c]     = (u16)u;
                kb[(r0 + v + 1) * 72 + c] = (u16)(u >> 16);
            }
        } else if (mat == 2) {
            *(unsigned int*)&avaT[c * 40 + r0]     = cvtpk(acc[p][0], acc[p][1]);
            *(unsigned int*)&avaT[c * 40 + r0 + 2] = cvtpk(acc[p][2], acc[p][3]);
        } // mat==3 (avp) held in regs
    }
    __syncthreads();

    // ---- phase B: scores+softmax (waves 0-1, DPP reduce) | diff (waves 12-15)
    bf16x8 pwg[2];
    if (wave >= 8) {
        const int nt = (wave - 8) & 3;
        const u16* wgp = wTg + (h * 64 + nt * 16 + l16) * 64;
        #pragma unroll
        for (int ks = 0; ks < 2; ks++)
            pwg[ks] = *(const bf16x8*)&wgp[ks * 32 + q16 * 8];
    }
    if (wave < 2) {
        const int mt = wave;
        f32x4 s0 = {0.f,0.f,0.f,0.f}, s1 = {0.f,0.f,0.f,0.f};
        #pragma unroll
        for (int ks = 0; ks < 2; ks++) {
            const bf16x8 af = *(const bf16x8*)&qb[(mt * 16 + l16) * 72 + ks * 32 + q16 * 8];
            const bf16x8 b0 = *(const bf16x8*)&kb[l16 * 72 + ks * 32 + q16 * 8];
            const bf16x8 b1 = *(const bf16x8*)&kb[(16 + l16) * 72 + ks * 32 + q16 * 8];
            s0 = __builtin_amdgcn_mfma_f32_16x16x32_bf16(af, b0, s0, 0, 0, 0);
            s1 = __builtin_amdgcn_mfma_f32_16x16x32_bf16(af, b1, s1, 0, 0, 0);
        }
        #pragma unroll
        for (int v = 0; v < 4; v++) {
            float a0 = s0[v] * 0.125f, a1 = s1[v] * 0.125f;
            // 16-lane rotate-reduce on VALU pipe (l16 groups == DPP rows)
            float mx = fmaxf(a0, a1);
            mx = dppmax<ROR1>(mx); mx = dppmax<ROR2>(mx);
            mx = dppmax<ROR4>(mx); mx = dppmax<ROR8>(mx);
            float e0 = __expf(a0 - mx), e1 = __expf(a1 - mx);
            float sm = e0 + e1;
            sm = dppadd<ROR1>(sm); sm = dppadd<ROR2>(sm);
            sm = dppadd<ROR4>(sm); sm = dppadd<ROR8>(sm);
            const float inv = 1.f / sm;
            e0 *= inv; e1 *= inv;
            const int i = mt * 16 + q16 * 4 + v;
            const unsigned int uw = cvtpk(e0, e1);
            wb[i * 40 + l16]      = (u16)uw;
            wb[i * 40 + 16 + l16] = (u16)(uw >> 16);
            wo[v * 2]     = e0;          // deferred w_out store
            wo[v * 2 + 1] = e1;
        }
    } else if (wave >= 12) {
        #pragma unroll
        for (int p = 0; p < 2; p++) {
            const int tau = wave * 2 + p;
            const int mt  = (tau >> 2) & 1, nt = tau & 3;
            const int c   = nt * 16 + l16;
            const int r0  = mt * 16 + q16 * 4;
            #pragma unroll
            for (int v = 0; v < 4; v += 2) {
                const float av0 = bf2f(avaT[c * 40 + (r0 + v)]);
                const float av1 = bf2f(avaT[c * 40 + (r0 + v + 1)]);
                const unsigned int u = cvtpk(acc[p][v] - av0, acc[p][v + 1] - av1);
                diffb[(r0 + v) * 72 + c]     = (u16)u;
                diffb[(r0 + v + 1) * 72 + c] = (u16)(u >> 16);
            }
        }
    }
    __syncthreads();

    // ---- phase C: S = w@ava (waves 0-7) | DG = diff@Wg (waves 8-15, store
    //      deferred). No global stores before the next barrier.
    if (wave < 8) {
        const int mt = wave >> 2, nt = wave & 3;
        const bf16x8 af = *(const bf16x8*)&wb[(mt * 16 + l16) * 40 + q16 * 8];
        const bf16x8 bf = *(const bf16x8*)&avaT[(nt * 16 + l16) * 40 + q16 * 8];
        f32x4 a = {0.f, 0.f, 0.f, 0.f};
        a = __builtin_amdgcn_mfma_f32_16x16x32_bf16(af, bf, a, 0, 0, 0);
        const int c = nt * 16 + l16, r0 = mt * 16 + q16 * 4;
        #pragma unroll
        for (int v = 0; v < 4; v += 2) {
            S32[(r0 + v) * 68 + c]     = a[v];
            S32[(r0 + v + 1) * 68 + c] = a[v + 1];
            const unsigned int u = cvtpk(a[v], a[v + 1]);
            Sb[(r0 + v) * 72 + c]     = (u16)u;
            Sb[(r0 + v + 1) * 72 + c] = (u16)(u >> 16);
        }
    } else {
        const int w8 = wave - 8;
        const int mt = w8 >> 2;
        f32x4 a = {0.f, 0.f, 0.f, 0.f};
        #pragma unroll
        for (int ks = 0; ks < 2; ks++) {
            const bf16x8 af = *(const bf16x8*)&diffb[(mt * 16 + l16) * 72 + ks * 32 + q16 * 8];
            a = __builtin_amdgcn_mfma_f32_16x16x32_bf16(af, pwg[ks], a, 0, 0, 0);
        }
        dg_a = a;   // deferred store
    }
    __syncthreads();

    // ---- phase D: dotSD (waves 0-3) | SG+DG stores (waves 8-15) |
    //      sumS (wave 4, lanes 0-31) | sumD (wave 5, lanes 0-31; moved here
    //      from phase C: off wave-0's critical path, onto an idle wave, and
    //      its store no longer precedes any barrier)
    if (wave < 4) {
        const int mt = wave >> 1, nt = wave & 1;
        f32x4 a = {0.f, 0.f, 0.f, 0.f};
        #pragma unroll
        for (int ks = 0; ks < 2; ks++) {
            const bf16x8 af = *(const bf16x8*)&Sb[(mt * 16 + l16) * 72 + ks * 32 + q16 * 8];
            const bf16x8 bf = *(const bf16x8*)&diffb[(nt * 16 + l16) * 72 + ks * 32 + q16 * 8];
            a = __builtin_amdgcn_mfma_f32_16x16x32_bf16(af, bf, a, 0, 0, 0);
        }
        const int j = nt * 16 + l16, r0 = mt * 16 + q16 * 4;
        #pragma unroll
        for (int v = 0; v < 4; v++)
            dotSD[(bh * 32 + r0 + v) * 32 + j] = a[v];
    } else if (wave >= 8) {
        const int w8 = wave - 8;
        const int mt = w8 >> 2, nt = w8 & 3;
        f32x4 a = {0.f, 0.f, 0.f, 0.f};
        #pragma unroll
        for (int ks = 0; ks < 2; ks++) {
            const bf16x8 af = *(const bf16x8*)&Sb[(mt * 16 + l16) * 72 + ks * 32 + q16 * 8];
            a = __builtin_amdgcn_mfma_f32_16x16x32_bf16(af, pwg[ks], a, 0, 0, 0);
        }
        const int c = nt * 16 + l16, r0 = mt * 16 + q16 * 4;
        #pragma unroll
        for (int v = 0; v < 4; v++)
            SG[(bh * 32 + r0 + v) * 64 + c] = a[v];
        #pragma unroll
        for (int v = 0; v < 4; v++)
            DG[(bh * 32 + r0 + v) * 64 + c] = dg_a[v];   // deferred from C
    } else if (t >= 256 && t < 288) {
        const int r = t - 256;
        float s1 = 0.f, s2 = 0.f;
        #pragma unroll
        for (int e4 = 0; e4 < 16; e4++) {
            const float4 v4 = *(const float4*)&S32[r * 68 + e4 * 4];
            s1 += v4.x + v4.y + v4.z + v4.w;
            s2 += v4.x * v4.x + v4.y * v4.y + v4.z * v4.z + v4.w * v4.w;
        }
        sumS[bh * 32 + r] = s1; sumS2[bh * 32 + r] = s2;
    } else if (t >= 320 && t < 352) {
        const int r = t - 320;
        float s1 = 0.f, s2 = 0.f;
        #pragma unroll
        for (int e8 = 0; e8 < 8; e8++) {
            const uint4 u = *(const uint4*)&diffb[r * 72 + e8 * 8];
            const unsigned int uu[4] = {u.x, u.y, u.z, u.w};
            #pragma unroll
            for (int q = 0; q < 4; q++) {
                const float fl = __uint_as_float(uu[q] << 16);
                const float fh = __uint_as_float(uu[q] & 0xffff0000u);
                s1 += fl + fh;
                s2 += fl * fl + fh * fh;
            }
        }
        sumD[bh * 32 + r] = s1; sumD2[bh * 32 + r] = s2;
    }

    // ---- deferred w_out stores (waves 0-1; after all barriers)
    if (wave < 2) {
        const int mt = wave;
        #pragma unroll
        for (int v = 0; v < 4; v++) {
            const int i = mt * 16 + q16 * 4 + v;
            w_out[(bh * 32 + i) * 32 + l16]      = wo[v * 2];
            w_out[(bh * 32 + i) * 32 + 16 + l16] = wo[v * 2 + 1];
        }
    }
}

// ---------------------------------------------------------------------------
// Kernel C (1024 blocks: b x 4 i-groups x 2 j-groups; 256 threads). Unchanged.
// ---------------------------------------------------------------------------
__global__ __launch_bounds__(256) void kC(
    const float* __restrict__ SG, const float* __restrict__ DG,
    const float* __restrict__ sumS, const float* __restrict__ sumS2,
    const float* __restrict__ sumD, const float* __restrict__ sumD2,
    const float* __restrict__ dotSD, const float* __restrict__ w_all,
    const float* __restrict__ GW, const float* __restrict__ BW,
    const float* __restrict__ W_f2, float* __restrict__ value)
{
    const int blk = blockIdx.x;          // b*8 + ig*2 + jg
    const int b   = blk >> 3;
    const int i0  = ((blk >> 1) & 3) * 8;
    const int j0  = (blk & 1) * 16;
    const int t   = threadIdx.x;
    const int w0  = t >> 6;              // 0..3
    const int e   = t & 63;

    __shared__ alignas(16) float pk[8 * 16 * 12];   // [ii][jl][hh*3 + {a,b,c}]

    for (int idx = t; idx < 512; idx += 256) {
        const int ii = idx >> 6, jl = (idx >> 2) & 15, hh = idx & 3;
        const int j  = j0 + jl;
        const int hi = (b * 4 + hh) * 32 + i0 + ii;
        const int hj = (b * 4 + hh) * 32 + j;
        const float wv  = w_all[hi * 32 + j];
        const float dsd = dotSD[hi * 32 + j];
        const float mu  = (sumS[hi] + wv * sumD[hj]) * (1.f / 64.f);
        const float e2  = (sumS2[hi] + 2.f * wv * dsd + wv * wv * sumD2[hj]) * (1.f / 64.f);
        const float var = fmaxf(e2 - mu * mu, 0.f);
        const float inv = rsqrtf(var + LN_EPS);
        float* rec = &pk[(ii * 16 + jl) * 12 + hh * 3];
        rec[0] = inv;
        rec[1] = inv * wv;
        rec[2] = -inv * mu;
    }

    const float bwr = BW[e];
    const float f2v = W_f2[e];
    float gw[4], sg[8][4];
    #pragma unroll
    for (int hh = 0; hh < 4; hh++) {
        gw[hh] = GW[hh * 64 + e];
        #pragma unroll
        for (int ii = 0; ii < 8; ii++)
            sg[ii][hh] = SG[((b * 4 + hh) * 32 + i0 + ii) * 64 + e];
    }
    __syncthreads();

    for (int jb = 0; jb < 4; jb++) {
        const int jl = jb * 4 + w0;      // 0..15, wave-uniform
        const int j  = j0 + jl;
        float d[4];
        #pragma unroll
        for (int hh = 0; hh < 4; hh++)
            d[hh] = DG[((b * 4 + hh) * 32 + j) * 64 + e];
        #pragma unroll
        for (int ii = 0; ii < 8; ii++) {
            const float* rec = &pk[(ii * 16 + jl) * 12];
            const f32x4 r0 = *(const f32x4*)rec;         // a0 b0 c0 a1
            const f32x4 r1 = *(const f32x4*)(rec + 4);   // b1 c1 a2 b2
            const f32x4 r2 = *(const f32x4*)(rec + 8);   // c2 a3 b3 c3
            float z = bwr;
            z += r0[0] * sg[ii][0]; z += r0[1] * d[0]; z += r0[2] * gw[0];
            z += r0[3] * sg[ii][1]; z += r1[0] * d[1]; z += r1[1] * gw[1];
            z += r1[2] * sg[ii][2]; z += r1[3] * d[2]; z += r2[0] * gw[2];
            z += r2[1] * sg[ii][3]; z += r2[2] * d[3]; z += r2[3] * gw[3];
            float p = leaky(z) * f2v;
            p = dppadd<0x111>(p);
            p = dppadd<0x112>(p);
            p = dppadd<0x114>(p);
            p = dppadd<0x118>(p);
            p = dppadd<0x142>(p);
            p = dppadd<0x143>(p);
            if (e == 63) value[(b * 32 + i0 + ii) * 32 + j] = p;
        }
    }
}

extern "C" void kernel_launch(void* const* d_in, const int* in_sizes, int n_in,
                              void* d_out, int out_size, void* d_ws, size_t ws_size,
                              hipStream_t stream)
{
    const float* states   = (const float*)d_in[0];
    const float* policies = (const float*)d_in[1];
    const float* actions  = (const float*)d_in[2];
    const float* W_se     = (const float*)d_in[3];
    const float* b_se     = (const float*)d_in[4];
    const float* W_sape   = (const float*)d_in[5];
    const float* b_sape   = (const float*)d_in[6];
    const float* Wk       = (const float*)d_in[7];
    const float* Wq       = (const float*)d_in[8];
    const float* Wv       = (const float*)d_in[9];
    const float* ln_g     = (const float*)d_in[10];
    const float* ln_b     = (const float*)d_in[11];
    const float* W_f1     = (const float*)d_in[12];
    const float* W_f2     = (const float*)d_in[13];

    float* out_value = (float*)d_out;
    float* out_w     = out_value + B * N * N;

    float* ws    = (float*)d_ws;
    float* SG    = ws;                       // 1,048,576
    float* DG    = SG    + 1048576;          // 1,048,576
    float* sumS  = DG    + 1048576;          // 16,384
    float* sumS2 = sumS  + 16384;
    float* sumD  = sumS2 + 16384;
    float* sumD2 = sumD  + 16384;
    float* dotSD = sumD2 + 16384;            // 524,288
    float* GW    = dotSD + 524288;           // 256
    float* BW    = GW    + 256;              // 64
    u16*   wTb   = (u16*)(BW + 64);          // 98,304
    u16*   wseT  = wTb   + 98304;            // 16,384
    u16*   wsapeT= wseT  + 16384;            // 16,384
    u16*   sapeTail = wsapeT + 16384;        // 4,096
    u16*   wTg   = sapeTail + 4096;          // 16,384

    kP<<<20, 256, 0, stream>>>(Wk, Wq, Wv, W_se, W_sape, ln_g, ln_b, W_f1,
                               wTb, wseT, wsapeT, sapeTail, wTg, GW, BW);
    kB<<<B * H, 1024, 0, stream>>>(states, actions, policies, b_se, b_sape,
                                   wTb, wseT, wsapeT, sapeTail, wTg, out_w,
                                   SG, DG, sumS, sumS2, sumD, sumD2, dotSD);
    kC<<<B * 8, 256, 0, stream>>>(SG, DG, sumS, sumS2, sumD, sumD2, dotSD,
                                  out_w, GW, BW, W_f2, out_value);
}